// Round 9
// baseline (3437.366 us; speedup 1.0000x reference)
//
#include <hip/hip_runtime.h>
#include <hip/hip_bf16.h>
#include <math.h>

#define T_TOK 4096
#define HID   2560
#define NEXP  32
#define KTOP  6
#define FF    1536
#define SFF   3072
#define MAXP  (T_TOK*KTOP)

typedef __attribute__((ext_vector_type(8))) short short8;
typedef __attribute__((ext_vector_type(4))) float f32x4;

static __device__ __forceinline__ unsigned short f2bf(float x){
  return __builtin_bit_cast(unsigned short, (__bf16)x);
}

static __device__ __forceinline__ void gload_lds16(const void* g, void* l){
  __builtin_amdgcn_global_load_lds(
      (const __attribute__((address_space(1))) unsigned int*)g,
      (__attribute__((address_space(3))) unsigned int*)l, 16, 0, 0);
}

// ---------------- cast hidden fp32 -> bf16 ----------------
__global__ void k_cast_x(const float* __restrict__ x, unsigned short* __restrict__ xb){
  int i = (blockIdx.x * 256 + threadIdx.x) * 4;
  float4 v = *(const float4*)(x + i);
  ushort4 o;
  o.x = f2bf(v.x); o.y = f2bf(v.y); o.z = f2bf(v.z); o.w = f2bf(v.w);
  *(ushort4*)(xb + i) = o;
}

// ---------------- transpose + convert: fp32 [z][R][C] -> bf16 [z*outBS + [C][R]] ----------------
__global__ __launch_bounds__(256)
void k_transpose(const float* __restrict__ in, unsigned short* __restrict__ out,
                 const int R, const int C, const long long outBS){
  const size_t bi = (size_t)blockIdx.z * (size_t)R * C;
  const size_t bo = (size_t)blockIdx.z * (size_t)outBS;
  __shared__ unsigned short t2[64][72];
  const int r0 = blockIdx.y * 64, c0 = blockIdx.x * 64;
  const int tid = threadIdx.x;
  const int cr = tid & 15;
  const int rr = tid >> 4;
#pragma unroll
  for (int i = 0; i < 4; ++i){
    const int r = rr + 16*i;
    float4 v = *(const float4*)(in + bi + (size_t)(r0 + r)*C + c0 + cr*4);
    ushort4 p;
    p.x = f2bf(v.x); p.y = f2bf(v.y); p.z = f2bf(v.z); p.w = f2bf(v.w);
    *(ushort4*)(&t2[r][cr*4]) = p;
  }
  __syncthreads();
  const int rw = tid & 7;
  const int ro = tid >> 3;
#pragma unroll
  for (int i = 0; i < 2; ++i){
    const int c = ro + 32*i;
    ushort4 a, b;
    a.x = t2[rw*8+0][c]; a.y = t2[rw*8+1][c]; a.z = t2[rw*8+2][c]; a.w = t2[rw*8+3][c];
    b.x = t2[rw*8+4][c]; b.y = t2[rw*8+5][c]; b.z = t2[rw*8+6][c]; b.w = t2[rw*8+7][c];
    unsigned short* op = out + bo + (size_t)(c0 + c)*R + r0 + rw*8;
    *(ushort4*)(op)     = a;
    *(ushort4*)(op + 4) = b;
  }
}

// ---------------- router ----------------
__global__ void k_router(const float* __restrict__ x, const float* __restrict__ rw,
                         const float* __restrict__ rb, float* __restrict__ top_w,
                         int* __restrict__ top_i, int* __restrict__ counts){
  const int lane = threadIdx.x & 63;
  const int wv   = threadIdx.x >> 6;
  const int t    = blockIdx.x * 4 + wv;
  const float* xr = x + (size_t)t * HID;
  float xv[40];
#pragma unroll
  for (int i = 0; i < 40; ++i) xv[i] = xr[lane + 64*i];
  float sc[32];
  for (int e = 0; e < 32; ++e){
    const float* w = rw + (size_t)e * HID;
    float s = 0.f;
#pragma unroll
    for (int i = 0; i < 40; ++i) s = fmaf(xv[i], w[lane + 64*i], s);
#pragma unroll
    for (int o = 32; o; o >>= 1) s += __shfl_xor(s, o);
    sc[e] = s;
  }
  float mx = sc[0];
#pragma unroll
  for (int e = 1; e < 32; ++e) mx = fmaxf(mx, sc[e]);
  float se = 0.f;
#pragma unroll
  for (int e = 0; e < 32; ++e){ sc[e] = expf(sc[e] - mx); se += sc[e]; }
  const float inv = 1.f / se;
#pragma unroll
  for (int e = 0; e < 32; ++e) sc[e] = sc[e] * inv + rb[e];

  unsigned chosen = 0; float swv[KTOP]; int sid[KTOP]; float wsum = 0.f;
#pragma unroll
  for (int k = 0; k < KTOP; ++k){
    float bv = -1e30f; int bi = 0;
#pragma unroll
    for (int e = 0; e < 32; ++e){
      bool ok = !((chosen >> e) & 1u);
      if (ok && sc[e] > bv){ bv = sc[e]; bi = e; }
    }
    chosen |= 1u << bi; swv[k] = bv; sid[k] = bi; wsum += bv;
  }
  const float dn = fmaxf(wsum, 1e-12f);
  if (lane < KTOP){
    top_w[t*KTOP + lane] = swv[lane] / dn;
    top_i[t*KTOP + lane] = sid[lane];
    atomicAdd(counts + sid[lane], 1);
  }
}

__global__ void k_scan(const int* __restrict__ counts, int* __restrict__ offsets){
  if (threadIdx.x == 0){
    int a = 0;
    for (int e = 0; e < NEXP; ++e){ offsets[e] = a; a += counts[e]; }
    offsets[NEXP] = a;
  }
}

__global__ void k_scatter(const int* __restrict__ top_i, const float* __restrict__ top_w,
                          const int* __restrict__ offsets, int* __restrict__ cursor,
                          int* __restrict__ pair_tok, float* __restrict__ pair_w){
  const int t = blockIdx.x * 256 + threadIdx.x;
  if (t >= T_TOK) return;
#pragma unroll
  for (int k = 0; k < KTOP; ++k){
    int e = top_i[t*KTOP + k];
    int pos = offsets[e] + atomicAdd(cursor + e, 1);
    pair_tok[pos] = t;
    pair_w[pos]   = top_w[t*KTOP + k];
  }
}

// ---------------- fused gate+up+SwiGLU GEMM: BM=256, BN=128 (gate & up), 8 waves ----------------
// MFMA-first phases: frags for h+1 read at end of phase h; vmcnt(4) keeps slot h+2 complete.
// Covers expert tiles (gather, act out) AND shared tiles (sact out) in one grid.
__global__ __launch_bounds__(512, 2)
void k_gufused(const unsigned short* __restrict__ A,
               const unsigned short* __restrict__ gT, const unsigned short* __restrict__ uT,
               const unsigned short* __restrict__ sgT, const unsigned short* __restrict__ suT,
               unsigned short* __restrict__ act, unsigned short* __restrict__ sact,
               const int* __restrict__ pair_tok,
               const int* __restrict__ counts, const int* __restrict__ offsets)
{
  constexpr int K = HID;
  constexpr int NH = K >> 5;             // 80
  constexpr int EXPTILES = NEXP * (FF/128);  // 384
  const int total = gridDim.x;
  const int phys  = blockIdx.x;
  const int logical = (phys & 7) * (total >> 3) + (phys >> 3);
  const int mt   = logical & 15;
  const int rest = logical >> 4;

  int M, base, n0, N; bool gather;
  const unsigned short *Bg, *Bu; unsigned short* op;
  if (rest < EXPTILES){
    const int e = rest / (FF/128);
    n0 = (rest % (FF/128)) * 128;
    M = counts[e]; base = offsets[e]; gather = true;
    Bg = gT + (size_t)e * FF * HID; Bu = uT + (size_t)e * FF * HID;
    op = act; N = FF;
  } else {
    const int s = rest - EXPTILES;
    n0 = s * 128; M = T_TOK; base = 0; gather = false;
    Bg = sgT; Bu = suT; op = sact; N = SFF;
  }
  if (mt * 256 >= M) return;

  __shared__ unsigned short AS[4*8192];   // 64 KB: 4 slots x 256 rows x 32k
  __shared__ unsigned short BgS[4*4096];  // 32 KB: 4 slots x 128 rows x 32k
  __shared__ unsigned short BuS[4*4096];  // 32 KB

  const int tid  = threadIdx.x;
  const int lane = tid & 63;
  const int w    = tid >> 6;             // 0..7
  const int wr = w >> 1, wc = w & 1;     // 4x2 wave grid; wave out 64 x (64g + 64u)

  const int lrow = lane >> 2, lchunk = lane & 3;
  const int swz = (lchunk ^ ((lrow >> 1) & 3)) * 8;
  const unsigned short *ap0, *ap1, *bgp, *bup;
  {
    const int r0 = w*32 + lrow, r1 = w*32 + 16 + lrow;
    int i0 = min(mt*256 + r0, M - 1);
    int i1 = min(mt*256 + r1, M - 1);
    int rowA0 = gather ? pair_tok[base + i0] : i0;
    int rowA1 = gather ? pair_tok[base + i1] : i1;
    ap0 = A + (size_t)rowA0 * K + swz;
    ap1 = A + (size_t)rowA1 * K + swz;
    const int rb = w*16 + lrow;
    const int swzb = (lchunk ^ ((rb >> 1) & 3)) * 8;
    bgp = Bg + (size_t)(n0 + rb) * K + swzb;
    bup = Bu + (size_t)(n0 + rb) * K + swzb;
  }

  const f32x4 zero = {0.f,0.f,0.f,0.f};
  f32x4 accg[4][4], accu[4][4];
#pragma unroll
  for (int m = 0; m < 4; ++m)
#pragma unroll
    for (int n = 0; n < 4; ++n){ accg[m][n] = zero; accu[m][n] = zero; }

  const int fr = lane & 15;
  const int fg = ((lane >> 4) ^ ((lane >> 1) & 3)) * 16;
  short8 af[4], bg[4], bu[4];

#define GU_STAGE(h)                                                         \
  { const int _s = (h) & 3; const size_t _k = (size_t)(h) * 32;             \
    gload_lds16(ap0 + _k, (char*)AS  + _s*16384 + (w*32)*64);               \
    gload_lds16(ap1 + _k, (char*)AS  + _s*16384 + (w*32+16)*64);            \
    gload_lds16(bgp + _k, (char*)BgS + _s*8192  + (w*16)*64);               \
    gload_lds16(bup + _k, (char*)BuS + _s*8192  + (w*16)*64); }

#define GU_RFRAGS(h)                                                        \
  { const int _s = (h) & 3;                                                 \
    const char* _as = (const char*)AS  + _s*16384;                          \
    const char* _bg = (const char*)BgS + _s*8192;                           \
    const char* _bu = (const char*)BuS + _s*8192;                           \
    _Pragma("unroll")                                                       \
    for (int m = 0; m < 4; ++m)                                             \
      af[m] = *(const short8*)(_as + (wr*64 + m*16 + fr)*64 + fg);          \
    _Pragma("unroll")                                                       \
    for (int n = 0; n < 4; ++n){                                            \
      bg[n] = *(const short8*)(_bg + (wc*64 + n*16 + fr)*64 + fg);          \
      bu[n] = *(const short8*)(_bu + (wc*64 + n*16 + fr)*64 + fg); } }

  GU_STAGE(0) GU_STAGE(1) GU_STAGE(2)
  asm volatile("s_waitcnt vmcnt(4)" ::: "memory");
  __builtin_amdgcn_s_barrier();
  GU_RFRAGS(0)

#pragma unroll 4
  for (int h = 0; h < NH; ++h){
    __builtin_amdgcn_s_setprio(1);
#pragma unroll
    for (int m = 0; m < 4; ++m)
#pragma unroll
      for (int n = 0; n < 4; ++n){
        accg[m][n] = __builtin_amdgcn_mfma_f32_16x16x32_bf16(af[m], bg[n], accg[m][n], 0, 0, 0);
        accu[m][n] = __builtin_amdgcn_mfma_f32_16x16x32_bf16(af[m], bu[n], accu[m][n], 0, 0, 0);
      }
    __builtin_amdgcn_s_setprio(0);
    __builtin_amdgcn_sched_barrier(0);
    if (h + 3 < NH) GU_STAGE(h + 3)
    if (h + 1 < NH) GU_RFRAGS(h + 1)
    if (h + 3 < NH) asm volatile("s_waitcnt vmcnt(4)" ::: "memory");
    else            asm volatile("s_waitcnt vmcnt(0)" ::: "memory");
    __builtin_amdgcn_s_barrier();
  }
#undef GU_STAGE
#undef GU_RFRAGS

#pragma unroll
  for (int m = 0; m < 4; ++m)
#pragma unroll
    for (int j = 0; j < 4; ++j){
      const int rr = mt*256 + wr*64 + m*16 + (lane >> 4)*4 + j;
      if (rr < M){
        unsigned short* orow = op + (size_t)(base + rr) * N + n0 + wc*64 + fr;
#pragma unroll
        for (int n = 0; n < 4; ++n){
          float g = accg[m][n][j], u = accu[m][n][j];
          float s = (g / (1.f + expf(-g))) * u;
          orow[n*16] = f2bf(s);
        }
      }
    }
}

// ---------------- down GEMM: 256x256 tile, 8 waves, MFMA-first phases ----------------
// OUT: 1 = fp32 atomicAdd*pair_w to out[tok][HID]; 2 = fp32 store out[rr][N]
template<bool GROUPED, int OUT>
__global__ __launch_bounds__(512, 2)
void k_down(const unsigned short* __restrict__ Aact,
            const unsigned short* __restrict__ BT, float* __restrict__ outp,
            const int* __restrict__ pair_tok, const float* __restrict__ pair_w,
            const int* __restrict__ counts, const int* __restrict__ offsets,
            const int K)
{
  constexpr int N = HID;
  constexpr int ntiles = N >> 8;         // 10
  const int NH = K >> 5;
  const int total = gridDim.x;
  const int phys  = blockIdx.x;
  const int logical = (phys & 7) * (total >> 3) + (phys >> 3);
  const int mt   = logical & 15;
  const int rest = logical >> 4;
  const int n0 = (rest % ntiles) << 8;
  const int e  = rest / ntiles;

  int M, base;
  if (GROUPED){ M = counts[e]; base = offsets[e]; }
  else        { M = T_TOK;     base = 0; }
  if (mt * 256 >= M) return;
  const unsigned short* Bb = BT + (size_t)e * (size_t)N * K;

  __shared__ unsigned short AS[4*8192];  // 64 KB
  __shared__ unsigned short BS[4*8192];  // 64 KB

  const int tid  = threadIdx.x;
  const int lane = tid & 63;
  const int w    = tid >> 6;
  const int wr = w >> 2, wc = w & 3;     // 2x4 wave grid, wave out = 128x64

  const int lrow = lane >> 2, lchunk = lane & 3;
  const int swz = (lchunk ^ ((lrow >> 1) & 3)) * 8;
  const unsigned short *ap0, *ap1, *bp0, *bp1;
  {
    const int r0 = w*32 + lrow, r1 = w*32 + 16 + lrow;
    int i0 = min(mt*256 + r0, M - 1);
    int i1 = min(mt*256 + r1, M - 1);
    ap0 = Aact + (size_t)(base + i0) * K + swz;
    ap1 = Aact + (size_t)(base + i1) * K + swz;
    bp0 = Bb + (size_t)(n0 + r0) * K + swz;
    bp1 = Bb + (size_t)(n0 + r1) * K + swz;
  }

  const f32x4 zero = {0.f,0.f,0.f,0.f};
  f32x4 acc[8][4];
#pragma unroll
  for (int m = 0; m < 8; ++m)
#pragma unroll
    for (int n = 0; n < 4; ++n) acc[m][n] = zero;

  const int fr = lane & 15;
  const int fg = ((lane >> 4) ^ ((lane >> 1) & 3)) * 16;
  short8 af[8], bq[4];

#define DN_STAGE(h)                                                         \
  { const int _s = (h) & 3; const size_t _k = (size_t)(h) * 32;             \
    gload_lds16(ap0 + _k, (char*)AS + _s*16384 + (w*32)*64);                \
    gload_lds16(ap1 + _k, (char*)AS + _s*16384 + (w*32+16)*64);             \
    gload_lds16(bp0 + _k, (char*)BS + _s*16384 + (w*32)*64);                \
    gload_lds16(bp1 + _k, (char*)BS + _s*16384 + (w*32+16)*64); }

#define DN_RFRAGS(h)                                                        \
  { const int _s = (h) & 3;                                                 \
    const char* _as = (const char*)AS + _s*16384;                           \
    const char* _bs = (const char*)BS + _s*16384;                           \
    _Pragma("unroll")                                                       \
    for (int m = 0; m < 8; ++m)                                             \
      af[m] = *(const short8*)(_as + (wr*128 + m*16 + fr)*64 + fg);         \
    _Pragma("unroll")                                                       \
    for (int n = 0; n < 4; ++n)                                             \
      bq[n] = *(const short8*)(_bs + (wc*64 + n*16 + fr)*64 + fg); }

  DN_STAGE(0) DN_STAGE(1) DN_STAGE(2)
  asm volatile("s_waitcnt vmcnt(4)" ::: "memory");
  __builtin_amdgcn_s_barrier();
  DN_RFRAGS(0)

#pragma unroll 4
  for (int h = 0; h < NH; ++h){
    __builtin_amdgcn_s_setprio(1);
#pragma unroll
    for (int m = 0; m < 8; ++m)
#pragma unroll
      for (int n = 0; n < 4; ++n)
        acc[m][n] = __builtin_amdgcn_mfma_f32_16x16x32_bf16(af[m], bq[n], acc[m][n], 0, 0, 0);
    __builtin_amdgcn_s_setprio(0);
    __builtin_amdgcn_sched_barrier(0);
    if (h + 3 < NH) DN_STAGE(h + 3)
    if (h + 1 < NH) DN_RFRAGS(h + 1)
    if (h + 3 < NH) asm volatile("s_waitcnt vmcnt(4)" ::: "memory");
    else            asm volatile("s_waitcnt vmcnt(0)" ::: "memory");
    __builtin_amdgcn_s_barrier();
  }
#undef DN_STAGE
#undef DN_RFRAGS

#pragma unroll
  for (int m = 0; m < 8; ++m)
#pragma unroll
    for (int j = 0; j < 4; ++j){
      const int rr = mt*256 + wr*128 + m*16 + (lane >> 4)*4 + j;
      if (rr < M){
        const int col = n0 + wc*64 + fr;
        if (OUT == 1){
          const int p = base + rr;
          const int tok = pair_tok[p];
          const float pw = pair_w[p];
          float* orow = outp + (size_t)tok * HID + col;
#pragma unroll
          for (int n = 0; n < 4; ++n) atomicAdd(orow + n*16, acc[m][n][j] * pw);
        } else {
          float* orow = outp + (size_t)rr * N + col;
#pragma unroll
          for (int n = 0; n < 4; ++n) orow[n*16] = acc[m][n][j];
        }
      }
    }
}

extern "C" void kernel_launch(void* const* d_in, const int* in_sizes, int n_in,
                              void* d_out, int out_size, void* d_ws, size_t ws_size,
                              hipStream_t stream)
{
  (void)in_sizes; (void)n_in; (void)out_size; (void)ws_size;
  const float* hid = (const float*)d_in[0];
  const float* rw  = (const float*)d_in[1];
  const float* rb  = (const float*)d_in[2];
  const float* gw  = (const float*)d_in[3];
  const float* uw  = (const float*)d_in[4];
  const float* dw  = (const float*)d_in[5];
  const float* sgw = (const float*)d_in[6];
  const float* suw = (const float*)d_in[7];
  const float* sdw = (const float*)d_in[8];
  float* out = (float*)d_out;

  char* ws = (char*)d_ws;
  size_t o = 0;
  unsigned short* xb   = (unsigned short*)(ws + o); o += (size_t)T_TOK*HID*2;   // 21 MB
  unsigned short* act  = (unsigned short*)(ws + o); o += (size_t)MAXP*FF*2;     // 75.5 MB
  unsigned short* sact = (unsigned short*)(ws + o); o += (size_t)T_TOK*SFF*2;   // 25 MB
  unsigned short* Wbuf = (unsigned short*)(ws + o);
  unsigned short* gT  = Wbuf;                                   // [32][F][H]
  unsigned short* uT  = Wbuf + (size_t)NEXP*FF*HID;             // [32][F][H]
  unsigned short* sgT = Wbuf + (size_t)2*NEXP*FF*HID;           // [SF][H]
  unsigned short* suT = sgT + (size_t)SFF*HID;                  // [SF][H]
  unsigned short* dT  = Wbuf;                                   // [32][H][F] (reuses gT)
  unsigned short* sdT = Wbuf + (size_t)NEXP*FF*HID;             // [H][SF]   (reuses uT)
  o += (size_t)2*NEXP*FF*HID*2 + (size_t)2*SFF*HID*2;           // 535 MB
  float* top_w    = (float*)(ws + o); o += (size_t)T_TOK*KTOP*4;
  int*   top_i    = (int*)(ws + o);   o += (size_t)T_TOK*KTOP*4;
  float* pair_w   = (float*)(ws + o); o += (size_t)MAXP*4;
  int*   pair_tok = (int*)(ws + o);   o += (size_t)MAXP*4;
  int*   counts   = (int*)(ws + o);   o += NEXP*4;
  int*   offsets  = (int*)(ws + o);   o += (NEXP+1)*4;
  int*   cursor   = (int*)(ws + o);   o += NEXP*4;

  hipMemsetAsync(counts, 0, (NEXP + (NEXP+1) + NEXP) * sizeof(int), stream);

  k_cast_x<<<(T_TOK*HID)/1024, 256, 0, stream>>>(hid, xb);
  k_router<<<T_TOK/4, 256, 0, stream>>>(hid, rw, rb, top_w, top_i, counts);
  k_scan<<<1, 64, 0, stream>>>(counts, offsets);
  k_scatter<<<T_TOK/256, 256, 0, stream>>>(top_i, top_w, offsets, cursor, pair_tok, pair_w);

  // phase A transposes: gate/up (expert + shared)
  k_transpose<<<dim3(FF/64,  HID/64, NEXP), 256, 0, stream>>>(gw,  gT,  HID, FF,  (long long)FF*HID);
  k_transpose<<<dim3(FF/64,  HID/64, NEXP), 256, 0, stream>>>(uw,  uT,  HID, FF,  (long long)FF*HID);
  k_transpose<<<dim3(SFF/64, HID/64, 1),    256, 0, stream>>>(sgw, sgT, HID, SFF, 0);
  k_transpose<<<dim3(SFF/64, HID/64, 1),    256, 0, stream>>>(suw, suT, HID, SFF, 0);

  // fused gate+up+SwiGLU, expert + shared in one grid
  k_gufused<<<16*(NEXP*(FF/128) + SFF/128), 512, 0, stream>>>(
      xb, gT, uT, sgT, suT, act, sact, pair_tok, counts, offsets);

  // phase B transposes: down (reuse gate/up region)
  k_transpose<<<dim3(HID/64, FF/64,  NEXP), 256, 0, stream>>>(dw,  dT,  FF,  HID, (long long)HID*FF);
  k_transpose<<<dim3(HID/64, SFF/64, 1),    256, 0, stream>>>(sdw, sdT, SFF, HID, 0);

  // down GEMMs: shared writes out (init), expert atomically accumulates
  k_down<false, 2><<<16*(HID/256), 512, 0, stream>>>(
      sact, sdT, out, nullptr, nullptr, nullptr, nullptr, SFF);
  k_down<true, 1><<<16*(HID/256)*NEXP, 512, 0, stream>>>(
      act, dT, out, pair_tok, pair_w, counts, offsets, FF);
}

// Round 10
// 2795.704 us; speedup vs baseline: 1.2295x; 1.2295x over previous
//
#include <hip/hip_runtime.h>
#include <hip/hip_bf16.h>
#include <math.h>

#define T_TOK 4096
#define HID   2560
#define NEXP  32
#define KTOP  6
#define FF    1536
#define SFF   3072
#define MAXP  (T_TOK*KTOP)

typedef __attribute__((ext_vector_type(8))) short short8;
typedef __attribute__((ext_vector_type(4))) float f32x4;

static __device__ __forceinline__ unsigned short f2bf(float x){
  return __builtin_bit_cast(unsigned short, (__bf16)x);
}

static __device__ __forceinline__ void gload_lds16(const void* g, void* l){
  __builtin_amdgcn_global_load_lds(
      (const __attribute__((address_space(1))) unsigned int*)g,
      (__attribute__((address_space(3))) unsigned int*)l, 16, 0, 0);
}

// ---------------- cast hidden fp32 -> bf16 ----------------
__global__ void k_cast_x(const float* __restrict__ x, unsigned short* __restrict__ xb){
  int i = (blockIdx.x * 256 + threadIdx.x) * 4;
  float4 v = *(const float4*)(x + i);
  ushort4 o;
  o.x = f2bf(v.x); o.y = f2bf(v.y); o.z = f2bf(v.z); o.w = f2bf(v.w);
  *(ushort4*)(xb + i) = o;
}

// ---- transpose+convert: fp32 [z][R][C] -> bf16 out[z*outBS + (colmul*c+coladd)*R + r] ----
__global__ __launch_bounds__(256)
void k_transpose(const float* __restrict__ in, unsigned short* __restrict__ out,
                 const int R, const int C, const long long outBS,
                 const int colmul, const int coladd){
  const size_t bi = (size_t)blockIdx.z * (size_t)R * C;
  const size_t bo = (size_t)blockIdx.z * (size_t)outBS;
  __shared__ unsigned short t2[64][72];
  const int r0 = blockIdx.y * 64, c0 = blockIdx.x * 64;
  const int tid = threadIdx.x;
  const int cr = tid & 15;
  const int rr = tid >> 4;
#pragma unroll
  for (int i = 0; i < 4; ++i){
    const int r = rr + 16*i;
    float4 v = *(const float4*)(in + bi + (size_t)(r0 + r)*C + c0 + cr*4);
    ushort4 p;
    p.x = f2bf(v.x); p.y = f2bf(v.y); p.z = f2bf(v.z); p.w = f2bf(v.w);
    *(ushort4*)(&t2[r][cr*4]) = p;
  }
  __syncthreads();
  const int rw = tid & 7;
  const int ro = tid >> 3;
#pragma unroll
  for (int i = 0; i < 2; ++i){
    const int c = ro + 32*i;
    ushort4 a, b;
    a.x = t2[rw*8+0][c]; a.y = t2[rw*8+1][c]; a.z = t2[rw*8+2][c]; a.w = t2[rw*8+3][c];
    b.x = t2[rw*8+4][c]; b.y = t2[rw*8+5][c]; b.z = t2[rw*8+6][c]; b.w = t2[rw*8+7][c];
    unsigned short* op = out + bo + (size_t)(colmul*(c0 + c) + coladd)*R + r0 + rw*8;
    *(ushort4*)(op)     = a;
    *(ushort4*)(op + 4) = b;
  }
}

// ---------------- router ----------------
__global__ void k_router(const float* __restrict__ x, const float* __restrict__ rw,
                         const float* __restrict__ rb, float* __restrict__ top_w,
                         int* __restrict__ top_i, int* __restrict__ counts){
  const int lane = threadIdx.x & 63;
  const int wv   = threadIdx.x >> 6;
  const int t    = blockIdx.x * 4 + wv;
  const float* xr = x + (size_t)t * HID;
  float xv[40];
#pragma unroll
  for (int i = 0; i < 40; ++i) xv[i] = xr[lane + 64*i];
  float sc[32];
  for (int e = 0; e < 32; ++e){
    const float* w = rw + (size_t)e * HID;
    float s = 0.f;
#pragma unroll
    for (int i = 0; i < 40; ++i) s = fmaf(xv[i], w[lane + 64*i], s);
#pragma unroll
    for (int o = 32; o; o >>= 1) s += __shfl_xor(s, o);
    sc[e] = s;
  }
  float mx = sc[0];
#pragma unroll
  for (int e = 1; e < 32; ++e) mx = fmaxf(mx, sc[e]);
  float se = 0.f;
#pragma unroll
  for (int e = 0; e < 32; ++e){ sc[e] = expf(sc[e] - mx); se += sc[e]; }
  const float inv = 1.f / se;
#pragma unroll
  for (int e = 0; e < 32; ++e) sc[e] = sc[e] * inv + rb[e];

  unsigned chosen = 0; float swv[KTOP]; int sid[KTOP]; float wsum = 0.f;
#pragma unroll
  for (int k = 0; k < KTOP; ++k){
    float bv = -1e30f; int bi = 0;
#pragma unroll
    for (int e = 0; e < 32; ++e){
      bool ok = !((chosen >> e) & 1u);
      if (ok && sc[e] > bv){ bv = sc[e]; bi = e; }
    }
    chosen |= 1u << bi; swv[k] = bv; sid[k] = bi; wsum += bv;
  }
  const float dn = fmaxf(wsum, 1e-12f);
  if (lane < KTOP){
    top_w[t*KTOP + lane] = swv[lane] / dn;
    top_i[t*KTOP + lane] = sid[lane];
    atomicAdd(counts + sid[lane], 1);
  }
}

__global__ void k_scan(const int* __restrict__ counts, int* __restrict__ offsets){
  if (threadIdx.x == 0){
    int a = 0;
    for (int e = 0; e < NEXP; ++e){ offsets[e] = a; a += counts[e]; }
    offsets[NEXP] = a;
  }
}

__global__ void k_scatter(const int* __restrict__ top_i, const float* __restrict__ top_w,
                          const int* __restrict__ offsets, int* __restrict__ cursor,
                          int* __restrict__ pair_tok, float* __restrict__ pair_w){
  const int t = blockIdx.x * 256 + threadIdx.x;
  if (t >= T_TOK) return;
#pragma unroll
  for (int k = 0; k < KTOP; ++k){
    int e = top_i[t*KTOP + k];
    int pos = offsets[e] + atomicAdd(cursor + e, 1);
    pair_tok[pos] = t;
    pair_w[pos]   = top_w[t*KTOP + k];
  }
}

// ---------------- gate+up GEMM with fused SwiGLU epilogue ----------------
// B = interleaved [gate;up] columns (even=gate f, odd=up f). Round-8 proven K-loop.
// Expert tiles (rest<384, gather, out=act) + shared tiles (out=sact) in one grid.
__global__ __launch_bounds__(512, 2)
void k_gu(const unsigned short* __restrict__ A,
          const unsigned short* __restrict__ guT, const unsigned short* __restrict__ sguT,
          unsigned short* __restrict__ act, unsigned short* __restrict__ sact,
          const int* __restrict__ pair_tok,
          const int* __restrict__ counts, const int* __restrict__ offsets)
{
  constexpr int K = HID;
  constexpr int NH = K >> 5;                 // 80
  constexpr int EXPT = NEXP * (2*FF/256);    // 384
  const int total = gridDim.x;
  const int phys  = blockIdx.x;
  const int logical = (phys & 7) * (total >> 3) + (phys >> 3);
  const int mt   = logical & 15;
  const int rest = logical >> 4;

  int M, base, n0, Fout; bool gather;
  const unsigned short* Bb; unsigned short* op;
  if (rest < EXPT){
    const int e = rest / 12;
    n0 = (rest % 12) << 8;
    M = counts[e]; base = offsets[e]; gather = true;
    Bb = guT + (size_t)e * (2*FF) * HID; op = act; Fout = FF;
  } else {
    const int s = rest - EXPT;
    n0 = s << 8; M = T_TOK; base = 0; gather = false;
    Bb = sguT; op = sact; Fout = SFF;
  }
  if (mt * 256 >= M) return;

  __shared__ unsigned short AS[4*8192];  // 64 KB
  __shared__ unsigned short BS[4*8192];  // 64 KB

  const int tid  = threadIdx.x;
  const int lane = tid & 63;
  const int w    = tid >> 6;
  const int wr = w >> 2, wc = w & 3;     // 2x4 wave grid, wave out = 128x64

  const int lrow = lane >> 2, lchunk = lane & 3;
  const int swz = (lchunk ^ ((lrow >> 1) & 3)) * 8;
  const unsigned short *ap0, *ap1, *bp0, *bp1;
  {
    const int r0 = w*32 + lrow, r1 = w*32 + 16 + lrow;
    int i0 = min(mt*256 + r0, M - 1);
    int i1 = min(mt*256 + r1, M - 1);
    int rowA0 = gather ? pair_tok[base + i0] : i0;
    int rowA1 = gather ? pair_tok[base + i1] : i1;
    ap0 = A + (size_t)rowA0 * K + swz;
    ap1 = A + (size_t)rowA1 * K + swz;
    bp0 = Bb + (size_t)(n0 + r0) * K + swz;
    bp1 = Bb + (size_t)(n0 + r1) * K + swz;
  }

  const f32x4 zero = {0.f,0.f,0.f,0.f};
  f32x4 acc[8][4];
#pragma unroll
  for (int m = 0; m < 8; ++m)
#pragma unroll
    for (int n = 0; n < 4; ++n) acc[m][n] = zero;

  const int fr = lane & 15;
  const int fg = ((lane >> 4) ^ ((lane >> 1) & 3)) * 16;

#define STAGE(h)                                                            \
  { const int _s = (h) & 3; const size_t _k = (size_t)(h) * 32;             \
    gload_lds16(ap0 + _k, (char*)AS + _s*16384 + (w*32)*64);                \
    gload_lds16(ap1 + _k, (char*)AS + _s*16384 + (w*32+16)*64);             \
    gload_lds16(bp0 + _k, (char*)BS + _s*16384 + (w*32)*64);                \
    gload_lds16(bp1 + _k, (char*)BS + _s*16384 + (w*32+16)*64); }

  STAGE(0) STAGE(1) STAGE(2)
  asm volatile("s_waitcnt vmcnt(8)" ::: "memory");
  __builtin_amdgcn_s_barrier();

#pragma unroll 4
  for (int h = 0; h < NH; ++h){
    const int s = h & 3;
    const char* _as = (const char*)AS + s*16384;
    const char* _bs = (const char*)BS + s*16384;
    short8 bq[4], af[8];
#pragma unroll
    for (int n = 0; n < 4; ++n)
      bq[n] = *(const short8*)(_bs + (wc*64 + n*16 + fr)*64 + fg);
#pragma unroll
    for (int m = 0; m < 8; ++m)
      af[m] = *(const short8*)(_as + (wr*128 + m*16 + fr)*64 + fg);
    if (h + 3 < NH) STAGE(h + 3)
    __builtin_amdgcn_s_setprio(1);
#pragma unroll
    for (int m = 0; m < 8; ++m)
#pragma unroll
      for (int n = 0; n < 4; ++n)
        acc[m][n] = __builtin_amdgcn_mfma_f32_16x16x32_bf16(af[m], bq[n], acc[m][n], 0, 0, 0);
    __builtin_amdgcn_s_setprio(0);
    if (h + 3 < NH)      asm volatile("s_waitcnt vmcnt(8)" ::: "memory");
    else if (h + 2 < NH) asm volatile("s_waitcnt vmcnt(4)" ::: "memory");
    else if (h + 1 < NH) asm volatile("s_waitcnt vmcnt(0)" ::: "memory");
    __builtin_amdgcn_s_barrier();
  }
#undef STAGE

  // fused SwiGLU epilogue: even lane holds gate, odd lane (same f) holds up
  const int fb = (n0 >> 1) + wc*32 + (fr >> 1);
#pragma unroll
  for (int m = 0; m < 8; ++m)
#pragma unroll
    for (int j = 0; j < 4; ++j){
      const int rr = mt*256 + wr*128 + m*16 + (lane >> 4)*4 + j;
      if (rr < M){
        unsigned short* orow = op + (size_t)(base + rr) * Fout + fb;
#pragma unroll
        for (int n = 0; n < 4; ++n){
          float g = acc[m][n][j];
          float u = __shfl_xor(g, 1);
          float sv = (g / (1.f + expf(-g))) * u;
          if (!(lane & 1)) orow[n*8] = f2bf(sv);
        }
      }
    }
}

// ---------------- down GEMM, atomic accumulate into out (pre-zeroed) ----------------
// Expert tiles (rest<320, A=act K=FF, *pair_w to out[tok]) + shared (A=sact K=SFF, pw=1).
__global__ __launch_bounds__(512, 2)
void k_dn(const unsigned short* __restrict__ act, const unsigned short* __restrict__ sact,
          const unsigned short* __restrict__ dT, const unsigned short* __restrict__ sdT,
          float* __restrict__ outp,
          const int* __restrict__ pair_tok, const float* __restrict__ pair_w,
          const int* __restrict__ counts, const int* __restrict__ offsets)
{
  constexpr int EXPT = NEXP * (HID/256);     // 320
  const int total = gridDim.x;
  const int phys  = blockIdx.x;
  const int logical = (phys & 7) * (total >> 3) + (phys >> 3);
  const int mt   = logical & 15;
  const int rest = logical >> 4;

  int M, base, n0, K; bool grouped;
  const unsigned short *Aarr, *Bb;
  if (rest < EXPT){
    const int e = rest / (HID/256);
    n0 = (rest % (HID/256)) << 8;
    M = counts[e]; base = offsets[e]; grouped = true;
    Aarr = act; K = FF; Bb = dT + (size_t)e * HID * FF;
  } else {
    const int s = rest - EXPT;
    n0 = s << 8; M = T_TOK; base = 0; grouped = false;
    Aarr = sact; K = SFF; Bb = sdT;
  }
  if (mt * 256 >= M) return;
  const int NH = K >> 5;

  __shared__ unsigned short AS[4*8192];
  __shared__ unsigned short BS[4*8192];

  const int tid  = threadIdx.x;
  const int lane = tid & 63;
  const int w    = tid >> 6;
  const int wr = w >> 2, wc = w & 3;

  const int lrow = lane >> 2, lchunk = lane & 3;
  const int swz = (lchunk ^ ((lrow >> 1) & 3)) * 8;
  const unsigned short *ap0, *ap1, *bp0, *bp1;
  {
    const int r0 = w*32 + lrow, r1 = w*32 + 16 + lrow;
    int i0 = min(mt*256 + r0, M - 1);
    int i1 = min(mt*256 + r1, M - 1);
    ap0 = Aarr + (size_t)(base + i0) * K + swz;
    ap1 = Aarr + (size_t)(base + i1) * K + swz;
    bp0 = Bb + (size_t)(n0 + r0) * K + swz;
    bp1 = Bb + (size_t)(n0 + r1) * K + swz;
  }

  const f32x4 zero = {0.f,0.f,0.f,0.f};
  f32x4 acc[8][4];
#pragma unroll
  for (int m = 0; m < 8; ++m)
#pragma unroll
    for (int n = 0; n < 4; ++n) acc[m][n] = zero;

  const int fr = lane & 15;
  const int fg = ((lane >> 4) ^ ((lane >> 1) & 3)) * 16;

#define STAGE(h)                                                            \
  { const int _s = (h) & 3; const size_t _k = (size_t)(h) * 32;             \
    gload_lds16(ap0 + _k, (char*)AS + _s*16384 + (w*32)*64);                \
    gload_lds16(ap1 + _k, (char*)AS + _s*16384 + (w*32+16)*64);             \
    gload_lds16(bp0 + _k, (char*)BS + _s*16384 + (w*32)*64);                \
    gload_lds16(bp1 + _k, (char*)BS + _s*16384 + (w*32+16)*64); }

  STAGE(0) STAGE(1) STAGE(2)
  asm volatile("s_waitcnt vmcnt(8)" ::: "memory");
  __builtin_amdgcn_s_barrier();

#pragma unroll 4
  for (int h = 0; h < NH; ++h){
    const int s = h & 3;
    const char* _as = (const char*)AS + s*16384;
    const char* _bs = (const char*)BS + s*16384;
    short8 bq[4], af[8];
#pragma unroll
    for (int n = 0; n < 4; ++n)
      bq[n] = *(const short8*)(_bs + (wc*64 + n*16 + fr)*64 + fg);
#pragma unroll
    for (int m = 0; m < 8; ++m)
      af[m] = *(const short8*)(_as + (wr*128 + m*16 + fr)*64 + fg);
    if (h + 3 < NH) STAGE(h + 3)
    __builtin_amdgcn_s_setprio(1);
#pragma unroll
    for (int m = 0; m < 8; ++m)
#pragma unroll
      for (int n = 0; n < 4; ++n)
        acc[m][n] = __builtin_amdgcn_mfma_f32_16x16x32_bf16(af[m], bq[n], acc[m][n], 0, 0, 0);
    __builtin_amdgcn_s_setprio(0);
    if (h + 3 < NH)      asm volatile("s_waitcnt vmcnt(8)" ::: "memory");
    else if (h + 2 < NH) asm volatile("s_waitcnt vmcnt(4)" ::: "memory");
    else if (h + 1 < NH) asm volatile("s_waitcnt vmcnt(0)" ::: "memory");
    __builtin_amdgcn_s_barrier();
  }
#undef STAGE

#pragma unroll
  for (int m = 0; m < 8; ++m)
#pragma unroll
    for (int j = 0; j < 4; ++j){
      const int rr = mt*256 + wr*128 + m*16 + (lane >> 4)*4 + j;
      if (rr < M){
        const int col = n0 + wc*64 + fr;
        int tok; float pw;
        if (grouped){ tok = pair_tok[base + rr]; pw = pair_w[base + rr]; }
        else        { tok = rr; pw = 1.f; }
        float* orow = outp + (size_t)tok * HID + col;
#pragma unroll
        for (int n = 0; n < 4; ++n) atomicAdd(orow + n*16, acc[m][n][j] * pw);
      }
    }
}

extern "C" void kernel_launch(void* const* d_in, const int* in_sizes, int n_in,
                              void* d_out, int out_size, void* d_ws, size_t ws_size,
                              hipStream_t stream)
{
  (void)in_sizes; (void)n_in; (void)out_size; (void)ws_size;
  const float* hid = (const float*)d_in[0];
  const float* rw  = (const float*)d_in[1];
  const float* rb  = (const float*)d_in[2];
  const float* gw  = (const float*)d_in[3];
  const float* uw  = (const float*)d_in[4];
  const float* dw  = (const float*)d_in[5];
  const float* sgw = (const float*)d_in[6];
  const float* suw = (const float*)d_in[7];
  const float* sdw = (const float*)d_in[8];
  float* out = (float*)d_out;

  char* ws = (char*)d_ws;
  size_t o = 0;
  unsigned short* xb   = (unsigned short*)(ws + o); o += (size_t)T_TOK*HID*2;   // 21 MB
  unsigned short* act  = (unsigned short*)(ws + o); o += (size_t)MAXP*FF*2;     // 75.5 MB
  unsigned short* sact = (unsigned short*)(ws + o); o += (size_t)T_TOK*SFF*2;   // 25 MB
  unsigned short* Wbuf = (unsigned short*)(ws + o);
  unsigned short* guT  = Wbuf;                                   // [32][2F(interleaved)][H]
  unsigned short* sguT = Wbuf + (size_t)NEXP*2*FF*HID;           // [2SF(interleaved)][H]
  unsigned short* dT   = Wbuf;                                   // [32][H][F] (reuse)
  unsigned short* sdT  = Wbuf + (size_t)NEXP*HID*FF;             // [H][SF]   (reuse)
  o += (size_t)NEXP*2*FF*HID*2 + (size_t)2*SFF*HID*2;            // 535 MB
  float* top_w    = (float*)(ws + o); o += (size_t)T_TOK*KTOP*4;
  int*   top_i    = (int*)(ws + o);   o += (size_t)T_TOK*KTOP*4;
  float* pair_w   = (float*)(ws + o); o += (size_t)MAXP*4;
  int*   pair_tok = (int*)(ws + o);   o += (size_t)MAXP*4;
  int*   counts   = (int*)(ws + o);   o += NEXP*4;
  int*   offsets  = (int*)(ws + o);   o += (NEXP+1)*4;
  int*   cursor   = (int*)(ws + o);   o += NEXP*4;

  hipMemsetAsync(counts, 0, (NEXP + (NEXP+1) + NEXP) * sizeof(int), stream);
  hipMemsetAsync(out, 0, (size_t)T_TOK*HID*sizeof(float), stream);

  k_cast_x<<<(T_TOK*HID)/1024, 256, 0, stream>>>(hid, xb);
  k_router<<<T_TOK/4, 256, 0, stream>>>(hid, rw, rb, top_w, top_i, counts);
  k_scan<<<1, 64, 0, stream>>>(counts, offsets);
  k_scatter<<<T_TOK/256, 256, 0, stream>>>(top_i, top_w, offsets, cursor, pair_tok, pair_w);

  // phase A transposes: interleaved [gate(even) | up(odd)] columns
  k_transpose<<<dim3(FF/64,  HID/64, NEXP), 256, 0, stream>>>(gw,  guT,  HID, FF,  (long long)2*FF*HID, 2, 0);
  k_transpose<<<dim3(FF/64,  HID/64, NEXP), 256, 0, stream>>>(uw,  guT,  HID, FF,  (long long)2*FF*HID, 2, 1);
  k_transpose<<<dim3(SFF/64, HID/64, 1),    256, 0, stream>>>(sgw, sguT, HID, SFF, 0, 2, 0);
  k_transpose<<<dim3(SFF/64, HID/64, 1),    256, 0, stream>>>(suw, sguT, HID, SFF, 0, 2, 1);

  // fused gate+up+SwiGLU (expert + shared in one grid)
  k_gu<<<16*(NEXP*(2*FF/256) + 2*SFF/256), 512, 0, stream>>>(
      xb, guT, sguT, act, sact, pair_tok, counts, offsets);

  // phase B transposes: down (reuse region)
  k_transpose<<<dim3(HID/64, FF/64,  NEXP), 256, 0, stream>>>(dw,  dT,  FF,  HID, (long long)HID*FF, 1, 0);
  k_transpose<<<dim3(HID/64, SFF/64, 1),    256, 0, stream>>>(sdw, sdT, SFF, HID, 0, 1, 0);

  // merged down (expert atomic*pair_w + shared atomic, out pre-zeroed)
  k_dn<<<16*(NEXP*(HID/256) + HID/256), 512, 0, stream>>>(
      act, sact, dT, sdT, out, pair_tok, pair_w, counts, offsets);
}

// Round 11
// 1884.485 us; speedup vs baseline: 1.8240x; 1.4835x over previous
//
#include <hip/hip_runtime.h>
#include <hip/hip_bf16.h>
#include <math.h>

#define T_TOK 4096
#define HID   2560
#define NEXP  32
#define KTOP  6
#define FF    1536
#define SFF   3072
#define MAXP  (T_TOK*KTOP)

typedef __attribute__((ext_vector_type(8))) short short8;
typedef __attribute__((ext_vector_type(4))) float f32x4;

static __device__ __forceinline__ unsigned short f2bf(float x){
  return __builtin_bit_cast(unsigned short, (__bf16)x);
}

static __device__ __forceinline__ void gload_lds16(const void* g, void* l){
  __builtin_amdgcn_global_load_lds(
      (const __attribute__((address_space(1))) unsigned int*)g,
      (__attribute__((address_space(3))) unsigned int*)l, 16, 0, 0);
}

// ---------------- cast hidden fp32 -> bf16 ----------------
__global__ void k_cast_x(const float* __restrict__ x, unsigned short* __restrict__ xb){
  int i = (blockIdx.x * 256 + threadIdx.x) * 4;
  float4 v = *(const float4*)(x + i);
  ushort4 o;
  o.x = f2bf(v.x); o.y = f2bf(v.y); o.z = f2bf(v.z); o.w = f2bf(v.w);
  *(ushort4*)(xb + i) = o;
}

// ---------------- transpose + convert: fp32 [z][R][C] -> bf16 [z*outBS + [C][R]] ----------------
__global__ __launch_bounds__(256)
void k_transpose(const float* __restrict__ in, unsigned short* __restrict__ out,
                 const int R, const int C, const long long outBS){
  const size_t bi = (size_t)blockIdx.z * (size_t)R * C;
  const size_t bo = (size_t)blockIdx.z * (size_t)outBS;
  __shared__ unsigned short t2[64][72];
  const int r0 = blockIdx.y * 64, c0 = blockIdx.x * 64;
  const int tid = threadIdx.x;
  const int cr = tid & 15;
  const int rr = tid >> 4;
#pragma unroll
  for (int i = 0; i < 4; ++i){
    const int r = rr + 16*i;
    float4 v = *(const float4*)(in + bi + (size_t)(r0 + r)*C + c0 + cr*4);
    ushort4 p;
    p.x = f2bf(v.x); p.y = f2bf(v.y); p.z = f2bf(v.z); p.w = f2bf(v.w);
    *(ushort4*)(&t2[r][cr*4]) = p;
  }
  __syncthreads();
  const int rw = tid & 7;
  const int ro = tid >> 3;
#pragma unroll
  for (int i = 0; i < 2; ++i){
    const int c = ro + 32*i;
    ushort4 a, b;
    a.x = t2[rw*8+0][c]; a.y = t2[rw*8+1][c]; a.z = t2[rw*8+2][c]; a.w = t2[rw*8+3][c];
    b.x = t2[rw*8+4][c]; b.y = t2[rw*8+5][c]; b.z = t2[rw*8+6][c]; b.w = t2[rw*8+7][c];
    unsigned short* op = out + bo + (size_t)(c0 + c)*R + r0 + rw*8;
    *(ushort4*)(op)     = a;
    *(ushort4*)(op + 4) = b;
  }
}

// ---------------- router ----------------
__global__ void k_router(const float* __restrict__ x, const float* __restrict__ rw,
                         const float* __restrict__ rb, float* __restrict__ top_w,
                         int* __restrict__ top_i, int* __restrict__ counts){
  const int lane = threadIdx.x & 63;
  const int wv   = threadIdx.x >> 6;
  const int t    = blockIdx.x * 4 + wv;
  const float* xr = x + (size_t)t * HID;
  float xv[40];
#pragma unroll
  for (int i = 0; i < 40; ++i) xv[i] = xr[lane + 64*i];
  float sc[32];
  for (int e = 0; e < 32; ++e){
    const float* w = rw + (size_t)e * HID;
    float s = 0.f;
#pragma unroll
    for (int i = 0; i < 40; ++i) s = fmaf(xv[i], w[lane + 64*i], s);
#pragma unroll
    for (int o = 32; o; o >>= 1) s += __shfl_xor(s, o);
    sc[e] = s;
  }
  float mx = sc[0];
#pragma unroll
  for (int e = 1; e < 32; ++e) mx = fmaxf(mx, sc[e]);
  float se = 0.f;
#pragma unroll
  for (int e = 0; e < 32; ++e){ sc[e] = expf(sc[e] - mx); se += sc[e]; }
  const float inv = 1.f / se;
#pragma unroll
  for (int e = 0; e < 32; ++e) sc[e] = sc[e] * inv + rb[e];

  unsigned chosen = 0; float swv[KTOP]; int sid[KTOP]; float wsum = 0.f;
#pragma unroll
  for (int k = 0; k < KTOP; ++k){
    float bv = -1e30f; int bi = 0;
#pragma unroll
    for (int e = 0; e < 32; ++e){
      bool ok = !((chosen >> e) & 1u);
      if (ok && sc[e] > bv){ bv = sc[e]; bi = e; }
    }
    chosen |= 1u << bi; swv[k] = bv; sid[k] = bi; wsum += bv;
  }
  const float dn = fmaxf(wsum, 1e-12f);
  if (lane < KTOP){
    top_w[t*KTOP + lane] = swv[lane] / dn;
    top_i[t*KTOP + lane] = sid[lane];
    atomicAdd(counts + sid[lane], 1);
  }
}

__global__ void k_scan(const int* __restrict__ counts, int* __restrict__ offsets){
  if (threadIdx.x == 0){
    int a = 0;
    for (int e = 0; e < NEXP; ++e){ offsets[e] = a; a += counts[e]; }
    offsets[NEXP] = a;
  }
}

__global__ void k_scatter(const int* __restrict__ top_i, const float* __restrict__ top_w,
                          const int* __restrict__ offsets, int* __restrict__ cursor,
                          int* __restrict__ pair_tok, float* __restrict__ pair_w){
  const int t = blockIdx.x * 256 + threadIdx.x;
  if (t >= T_TOK) return;
#pragma unroll
  for (int k = 0; k < KTOP; ++k){
    int e = top_i[t*KTOP + k];
    int pos = offsets[e] + atomicAdd(cursor + e, 1);
    pair_tok[pos] = t;
    pair_w[pos]   = top_w[t*KTOP + k];
  }
}

// ---------------- fused gate+up+SwiGLU GEMM: BM=256, BN=128, round-8 schedule ----------------
// B layout: guT[e] = [gate cols | up cols], each [col][K]. Wave = 64 rows x (64 g + 64 u cols).
// g and u accumulate in the SAME thread -> silu epilogue is register-local, no shfl.
template<bool EXP>
__global__ __launch_bounds__(512, 2)
void k_gufuse(const unsigned short* __restrict__ A,
              const unsigned short* __restrict__ guT,
              unsigned short* __restrict__ op,
              const int* __restrict__ pair_tok,
              const int* __restrict__ counts, const int* __restrict__ offsets,
              const int Fout)
{
  constexpr int K = HID;
  constexpr int NH = K >> 5;               // 80
  const int ntiles = Fout >> 7;            // 12 (exp) or 24 (shared)
  const int total = gridDim.x;
  const int phys  = blockIdx.x;
  const int logical = (phys & 7) * (total >> 3) + (phys >> 3);
  const int mt   = logical & 15;
  const int rest = logical >> 4;
  const int n0 = (rest % ntiles) << 7;
  const int e  = rest / ntiles;

  int M, base;
  if (EXP){ M = counts[e]; base = offsets[e]; }
  else    { M = T_TOK;     base = 0; }
  if (mt * 256 >= M) return;
  const unsigned short* Bb = guT + (size_t)e * (size_t)(2*Fout) * K;

  __shared__ unsigned short AS[4*8192];   // 64 KB: 4 slots x 256 rows x 32k
  __shared__ unsigned short BgS[4*4096];  // 32 KB: 4 slots x 128 rows x 32k
  __shared__ unsigned short BuS[4*4096];  // 32 KB

  const int tid  = threadIdx.x;
  const int lane = tid & 63;
  const int w    = tid >> 6;               // 0..7
  const int wr = w >> 1, wc = w & 1;       // 4x2 wave grid

  const int lrow = lane >> 2, lchunk = lane & 3;
  const unsigned short *ap0, *ap1, *bgp, *bup;
  {
    const int r0 = w*32 + lrow, r1 = w*32 + 16 + lrow;
    const int swza = (lchunk ^ ((r0 >> 1) & 3)) * 8;   // same key for r1 (r1 = r0+16)
    int i0 = min(mt*256 + r0, M - 1);
    int i1 = min(mt*256 + r1, M - 1);
    int rowA0 = EXP ? pair_tok[base + i0] : i0;
    int rowA1 = EXP ? pair_tok[base + i1] : i1;
    ap0 = A + (size_t)rowA0 * K + swza;
    ap1 = A + (size_t)rowA1 * K + swza;
    const int rb = w*16 + lrow;
    const int swzb = (lchunk ^ ((rb >> 1) & 3)) * 8;
    bgp = Bb + (size_t)(n0 + rb) * K + swzb;
    bup = Bb + (size_t)(Fout + n0 + rb) * K + swzb;
  }

  const f32x4 zero = {0.f,0.f,0.f,0.f};
  f32x4 accg[4][4], accu[4][4];
#pragma unroll
  for (int m = 0; m < 4; ++m)
#pragma unroll
    for (int n = 0; n < 4; ++n){ accg[m][n] = zero; accu[m][n] = zero; }

  const int fr = lane & 15;
  const int fg = ((lane >> 4) ^ ((lane >> 1) & 3)) * 16;

#define STAGE(h)                                                            \
  { const int _s = (h) & 3; const size_t _k = (size_t)(h) * 32;             \
    gload_lds16(ap0 + _k, (char*)AS  + _s*16384 + (w*32)*64);               \
    gload_lds16(ap1 + _k, (char*)AS  + _s*16384 + (w*32+16)*64);            \
    gload_lds16(bgp + _k, (char*)BgS + _s*8192  + (w*16)*64);               \
    gload_lds16(bup + _k, (char*)BuS + _s*8192  + (w*16)*64); }

  STAGE(0) STAGE(1) STAGE(2)
  asm volatile("s_waitcnt vmcnt(8)" ::: "memory");
  __builtin_amdgcn_s_barrier();

#pragma unroll 4
  for (int h = 0; h < NH; ++h){
    const int s = h & 3;
    const char* _as = (const char*)AS  + s*16384;
    const char* _bg = (const char*)BgS + s*8192;
    const char* _bu = (const char*)BuS + s*8192;
    short8 af[4], bg[4], bu[4];
#pragma unroll
    for (int n = 0; n < 4; ++n){
      bg[n] = *(const short8*)(_bg + (wc*64 + n*16 + fr)*64 + fg);
      bu[n] = *(const short8*)(_bu + (wc*64 + n*16 + fr)*64 + fg);
    }
#pragma unroll
    for (int m = 0; m < 4; ++m)
      af[m] = *(const short8*)(_as + (wr*64 + m*16 + fr)*64 + fg);
    if (h + 3 < NH) STAGE(h + 3)
    __builtin_amdgcn_s_setprio(1);
#pragma unroll
    for (int m = 0; m < 4; ++m)
#pragma unroll
      for (int n = 0; n < 4; ++n){
        accg[m][n] = __builtin_amdgcn_mfma_f32_16x16x32_bf16(af[m], bg[n], accg[m][n], 0, 0, 0);
        accu[m][n] = __builtin_amdgcn_mfma_f32_16x16x32_bf16(af[m], bu[n], accu[m][n], 0, 0, 0);
      }
    __builtin_amdgcn_s_setprio(0);
    if (h + 3 < NH)      asm volatile("s_waitcnt vmcnt(8)" ::: "memory");
    else if (h + 2 < NH) asm volatile("s_waitcnt vmcnt(4)" ::: "memory");
    else if (h + 1 < NH) asm volatile("s_waitcnt vmcnt(0)" ::: "memory");
    __builtin_amdgcn_s_barrier();
  }
#undef STAGE

#pragma unroll
  for (int m = 0; m < 4; ++m)
#pragma unroll
    for (int j = 0; j < 4; ++j){
      const int rr = mt*256 + wr*64 + m*16 + (lane >> 4)*4 + j;
      if (rr < M){
        unsigned short* orow = op + (size_t)(base + rr) * Fout + n0 + wc*64 + fr;
#pragma unroll
        for (int n = 0; n < 4; ++n){
          float g = accg[m][n][j], u = accu[m][n][j];
          float sv = (g / (1.f + expf(-g))) * u;
          orow[n*16] = f2bf(sv);
        }
      }
    }
}

// ---------------- down GEMM (round-8 verbatim): 256x256 tile, 8 waves ----------------
// OUT: 1 = fp32 atomicAdd*pair_w to out[tok][HID]; 2 = fp32 store out[rr][N]
template<bool GROUPED, bool GATHER, int OUT>
__global__ __launch_bounds__(512, 2)
void k_gemm(const unsigned short* __restrict__ A,
            const unsigned short* __restrict__ BT,
            void* __restrict__ outp,
            const int* __restrict__ pair_tok, const float* __restrict__ pair_w,
            const int* __restrict__ counts, const int* __restrict__ offsets,
            const int N, const int K, const int ntiles)
{
  const int NH = K >> 5;
  const int total = gridDim.x;
  const int phys  = blockIdx.x;
  const int logical = (phys & 7) * (total >> 3) + (phys >> 3);
  const int mt   = logical & 15;
  const int rest = logical >> 4;
  const int n0 = (rest % ntiles) << 8;
  const int e  = rest / ntiles;

  int M, base;
  if (GROUPED){ M = counts[e]; base = offsets[e]; }
  else        { M = T_TOK;     base = 0; }
  if (mt * 256 >= M) return;
  const unsigned short* Bb = BT + (size_t)e * (size_t)N * K;

  __shared__ unsigned short AS[4*8192];
  __shared__ unsigned short BS[4*8192];

  const int tid  = threadIdx.x;
  const int lane = tid & 63;
  const int w    = tid >> 6;
  const int wr = w >> 2, wc = w & 3;

  const int lrow = lane >> 2, lchunk = lane & 3;
  const int swz = (lchunk ^ ((lrow >> 1) & 3)) * 8;
  const unsigned short *ap0, *ap1, *bp0, *bp1;
  {
    const int r0 = w*32 + lrow, r1 = w*32 + 16 + lrow;
    int i0 = min(mt*256 + r0, M - 1);
    int i1 = min(mt*256 + r1, M - 1);
    int rowA0 = GATHER ? pair_tok[base + i0] : (GROUPED ? base + i0 : i0);
    int rowA1 = GATHER ? pair_tok[base + i1] : (GROUPED ? base + i1 : i1);
    ap0 = A + (size_t)rowA0 * K + swz;
    ap1 = A + (size_t)rowA1 * K + swz;
    bp0 = Bb + (size_t)(n0 + r0) * K + swz;
    bp1 = Bb + (size_t)(n0 + r1) * K + swz;
  }

  const f32x4 zero = {0.f,0.f,0.f,0.f};
  f32x4 acc[8][4];
#pragma unroll
  for (int m = 0; m < 8; ++m)
#pragma unroll
    for (int n = 0; n < 4; ++n) acc[m][n] = zero;

  const int fr = lane & 15;
  const int fg = ((lane >> 4) ^ ((lane >> 1) & 3)) * 16;

#define STAGE(h)                                                            \
  { const int _s = (h) & 3; const size_t _k = (size_t)(h) * 32;             \
    gload_lds16(ap0 + _k, (char*)AS + _s*16384 + (w*32)*64);                \
    gload_lds16(ap1 + _k, (char*)AS + _s*16384 + (w*32+16)*64);             \
    gload_lds16(bp0 + _k, (char*)BS + _s*16384 + (w*32)*64);                \
    gload_lds16(bp1 + _k, (char*)BS + _s*16384 + (w*32+16)*64); }

  STAGE(0) STAGE(1) STAGE(2)
  asm volatile("s_waitcnt vmcnt(8)" ::: "memory");
  __builtin_amdgcn_s_barrier();

#pragma unroll 4
  for (int h = 0; h < NH; ++h){
    const int s = h & 3;
    const char* _as = (const char*)AS + s*16384;
    const char* _bs = (const char*)BS + s*16384;
    short8 bq[4], af[8];
#pragma unroll
    for (int n = 0; n < 4; ++n)
      bq[n] = *(const short8*)(_bs + (wc*64 + n*16 + fr)*64 + fg);
#pragma unroll
    for (int m = 0; m < 8; ++m)
      af[m] = *(const short8*)(_as + (wr*128 + m*16 + fr)*64 + fg);
    if (h + 3 < NH) STAGE(h + 3)
    __builtin_amdgcn_s_setprio(1);
#pragma unroll
    for (int m = 0; m < 8; ++m)
#pragma unroll
      for (int n = 0; n < 4; ++n)
        acc[m][n] = __builtin_amdgcn_mfma_f32_16x16x32_bf16(af[m], bq[n], acc[m][n], 0, 0, 0);
    __builtin_amdgcn_s_setprio(0);
    if (h + 3 < NH)      asm volatile("s_waitcnt vmcnt(8)" ::: "memory");
    else if (h + 2 < NH) asm volatile("s_waitcnt vmcnt(4)" ::: "memory");
    else if (h + 1 < NH) asm volatile("s_waitcnt vmcnt(0)" ::: "memory");
    __builtin_amdgcn_s_barrier();
  }
#undef STAGE

#pragma unroll
  for (int m = 0; m < 8; ++m)
#pragma unroll
    for (int j = 0; j < 4; ++j){
      const int rr = mt*256 + wr*128 + m*16 + (lane >> 4)*4 + j;
      if (rr < M){
        const int col = n0 + wc*64 + fr;
        if (OUT == 1){
          const int p = base + rr;
          const int tok = pair_tok[p];
          const float pw = pair_w[p];
          float* orow = (float*)outp + (size_t)tok * HID + col;
#pragma unroll
          for (int n = 0; n < 4; ++n) atomicAdd(orow + n*16, acc[m][n][j] * pw);
        } else {
          float* orow = (float*)outp + (size_t)rr * N + col;
#pragma unroll
          for (int n = 0; n < 4; ++n) orow[n*16] = acc[m][n][j];
        }
      }
    }
}

extern "C" void kernel_launch(void* const* d_in, const int* in_sizes, int n_in,
                              void* d_out, int out_size, void* d_ws, size_t ws_size,
                              hipStream_t stream)
{
  (void)in_sizes; (void)n_in; (void)out_size; (void)ws_size;
  const float* hid = (const float*)d_in[0];
  const float* rw  = (const float*)d_in[1];
  const float* rb  = (const float*)d_in[2];
  const float* gw  = (const float*)d_in[3];
  const float* uw  = (const float*)d_in[4];
  const float* dw  = (const float*)d_in[5];
  const float* sgw = (const float*)d_in[6];
  const float* suw = (const float*)d_in[7];
  const float* sdw = (const float*)d_in[8];
  float* out = (float*)d_out;

  char* ws = (char*)d_ws;
  size_t o = 0;
  unsigned short* xb   = (unsigned short*)(ws + o); o += (size_t)T_TOK*HID*2;   // 21 MB
  unsigned short* act  = (unsigned short*)(ws + o); o += (size_t)MAXP*FF*2;     // 75.5 MB
  unsigned short* sact = (unsigned short*)(ws + o); o += (size_t)T_TOK*SFF*2;   // 25 MB
  unsigned short* Wbuf = (unsigned short*)(ws + o);
  unsigned short* guT  = Wbuf;                                   // [32][2F][H] (gate cols | up cols)
  unsigned short* sguT = Wbuf + (size_t)NEXP*2*FF*HID;           // [2SF][H]
  unsigned short* dT   = Wbuf;                                   // [32][H][F] (reuse)
  unsigned short* sdT  = Wbuf + (size_t)NEXP*HID*FF;             // [H][SF]   (reuse)
  o += (size_t)NEXP*2*FF*HID*2 + (size_t)2*SFF*HID*2;            // 535 MB
  float* top_w    = (float*)(ws + o); o += (size_t)T_TOK*KTOP*4;
  int*   top_i    = (int*)(ws + o);   o += (size_t)T_TOK*KTOP*4;
  float* pair_w   = (float*)(ws + o); o += (size_t)MAXP*4;
  int*   pair_tok = (int*)(ws + o);   o += (size_t)MAXP*4;
  int*   counts   = (int*)(ws + o);   o += NEXP*4;
  int*   offsets  = (int*)(ws + o);   o += (NEXP+1)*4;
  int*   cursor   = (int*)(ws + o);   o += NEXP*4;

  hipMemsetAsync(counts, 0, (NEXP + (NEXP+1) + NEXP) * sizeof(int), stream);

  k_cast_x<<<(T_TOK*HID)/1024, 256, 0, stream>>>(hid, xb);
  k_router<<<T_TOK/4, 256, 0, stream>>>(hid, rw, rb, top_w, top_i, counts);
  k_scan<<<1, 64, 0, stream>>>(counts, offsets);
  k_scatter<<<T_TOK/256, 256, 0, stream>>>(top_i, top_w, offsets, cursor, pair_tok, pair_w);

  // phase A transposes: gate cols then up cols, concatenated along N
  k_transpose<<<dim3(FF/64,  HID/64, NEXP), 256, 0, stream>>>(gw,  guT,                    HID, FF,  (long long)2*FF*HID);
  k_transpose<<<dim3(FF/64,  HID/64, NEXP), 256, 0, stream>>>(uw,  guT + (size_t)FF*HID,   HID, FF,  (long long)2*FF*HID);
  k_transpose<<<dim3(SFF/64, HID/64, 1),    256, 0, stream>>>(sgw, sguT,                   HID, SFF, 0);
  k_transpose<<<dim3(SFF/64, HID/64, 1),    256, 0, stream>>>(suw, sguT + (size_t)SFF*HID, HID, SFF, 0);

  // fused gate+up+SwiGLU GEMMs (expert, then shared)
  k_gufuse<true><<<16*(FF/128)*NEXP, 512, 0, stream>>>(
      xb, guT, act, pair_tok, counts, offsets, FF);
  k_gufuse<false><<<16*(SFF/128), 512, 0, stream>>>(
      xb, sguT, sact, nullptr, nullptr, nullptr, SFF);

  // phase B transposes: down (reuse gate/up region)
  k_transpose<<<dim3(HID/64, FF/64,  NEXP), 256, 0, stream>>>(dw,  dT,  FF,  HID, (long long)HID*FF);
  k_transpose<<<dim3(HID/64, SFF/64, 1),    256, 0, stream>>>(sdw, sdT, SFF, HID, 0);

  // down GEMMs: shared writes out (init), expert atomically accumulates
  k_gemm<false, false, 2><<<16*(HID/256), 512, 0, stream>>>(
      sact, sdT, out, nullptr, nullptr, nullptr, nullptr, HID, SFF, HID/256);
  k_gemm<true,  false, 1><<<16*(HID/256)*NEXP, 512, 0, stream>>>(
      act, dT, out, pair_tok, pair_w, counts, offsets, HID, FF, HID/256);
}

// Round 12
// 1875.214 us; speedup vs baseline: 1.8331x; 1.0049x over previous
//
#include <hip/hip_runtime.h>
#include <hip/hip_bf16.h>
#include <math.h>

#define T_TOK 4096
#define HID   2560
#define NEXP  32
#define KTOP  6
#define FF    1536
#define SFF   3072
#define MAXP  (T_TOK*KTOP)

typedef __attribute__((ext_vector_type(8))) short short8;
typedef __attribute__((ext_vector_type(4))) float f32x4;

static __device__ __forceinline__ unsigned short f2bf(float x){
  return __builtin_bit_cast(unsigned short, (__bf16)x);
}
static __device__ __forceinline__ float bf2f(unsigned short u){
  unsigned int x = ((unsigned int)u) << 16;
  return __builtin_bit_cast(float, x);
}

static __device__ __forceinline__ void gload_lds16(const void* g, void* l){
  __builtin_amdgcn_global_load_lds(
      (const __attribute__((address_space(1))) unsigned int*)g,
      (__attribute__((address_space(3))) unsigned int*)l, 16, 0, 0);
}

// ---------------- cast hidden fp32 -> bf16 ----------------
__global__ void k_cast_x(const float* __restrict__ x, unsigned short* __restrict__ xb){
  int i = (blockIdx.x * 256 + threadIdx.x) * 4;
  float4 v = *(const float4*)(x + i);
  ushort4 o;
  o.x = f2bf(v.x); o.y = f2bf(v.y); o.z = f2bf(v.z); o.w = f2bf(v.w);
  *(ushort4*)(xb + i) = o;
}

// ---------------- transpose + convert: fp32 [z][R][C] -> bf16 [z*outBS + [C][R]] ----------------
__global__ __launch_bounds__(256)
void k_transpose(const float* __restrict__ in, unsigned short* __restrict__ out,
                 const int R, const int C, const long long outBS){
  const size_t bi = (size_t)blockIdx.z * (size_t)R * C;
  const size_t bo = (size_t)blockIdx.z * (size_t)outBS;
  __shared__ unsigned short t2[64][72];
  const int r0 = blockIdx.y * 64, c0 = blockIdx.x * 64;
  const int tid = threadIdx.x;
  const int cr = tid & 15;
  const int rr = tid >> 4;
#pragma unroll
  for (int i = 0; i < 4; ++i){
    const int r = rr + 16*i;
    float4 v = *(const float4*)(in + bi + (size_t)(r0 + r)*C + c0 + cr*4);
    ushort4 p;
    p.x = f2bf(v.x); p.y = f2bf(v.y); p.z = f2bf(v.z); p.w = f2bf(v.w);
    *(ushort4*)(&t2[r][cr*4]) = p;
  }
  __syncthreads();
  const int rw = tid & 7;
  const int ro = tid >> 3;
#pragma unroll
  for (int i = 0; i < 2; ++i){
    const int c = ro + 32*i;
    ushort4 a, b;
    a.x = t2[rw*8+0][c]; a.y = t2[rw*8+1][c]; a.z = t2[rw*8+2][c]; a.w = t2[rw*8+3][c];
    b.x = t2[rw*8+4][c]; b.y = t2[rw*8+5][c]; b.z = t2[rw*8+6][c]; b.w = t2[rw*8+7][c];
    unsigned short* op = out + bo + (size_t)(c0 + c)*R + r0 + rw*8;
    *(ushort4*)(op)     = a;
    *(ushort4*)(op + 4) = b;
  }
}

// ---------------- router ----------------
__global__ void k_router(const float* __restrict__ x, const float* __restrict__ rw,
                         const float* __restrict__ rb, float* __restrict__ top_w,
                         int* __restrict__ top_i, int* __restrict__ counts){
  const int lane = threadIdx.x & 63;
  const int wv   = threadIdx.x >> 6;
  const int t    = blockIdx.x * 4 + wv;
  const float* xr = x + (size_t)t * HID;
  float xv[40];
#pragma unroll
  for (int i = 0; i < 40; ++i) xv[i] = xr[lane + 64*i];
  float sc[32];
  for (int e = 0; e < 32; ++e){
    const float* w = rw + (size_t)e * HID;
    float s = 0.f;
#pragma unroll
    for (int i = 0; i < 40; ++i) s = fmaf(xv[i], w[lane + 64*i], s);
#pragma unroll
    for (int o = 32; o; o >>= 1) s += __shfl_xor(s, o);
    sc[e] = s;
  }
  float mx = sc[0];
#pragma unroll
  for (int e = 1; e < 32; ++e) mx = fmaxf(mx, sc[e]);
  float se = 0.f;
#pragma unroll
  for (int e = 0; e < 32; ++e){ sc[e] = expf(sc[e] - mx); se += sc[e]; }
  const float inv = 1.f / se;
#pragma unroll
  for (int e = 0; e < 32; ++e) sc[e] = sc[e] * inv + rb[e];

  unsigned chosen = 0; float swv[KTOP]; int sid[KTOP]; float wsum = 0.f;
#pragma unroll
  for (int k = 0; k < KTOP; ++k){
    float bv = -1e30f; int bi = 0;
#pragma unroll
    for (int e = 0; e < 32; ++e){
      bool ok = !((chosen >> e) & 1u);
      if (ok && sc[e] > bv){ bv = sc[e]; bi = e; }
    }
    chosen |= 1u << bi; swv[k] = bv; sid[k] = bi; wsum += bv;
  }
  const float dn = fmaxf(wsum, 1e-12f);
  if (lane < KTOP){
    top_w[t*KTOP + lane] = swv[lane] / dn;
    top_i[t*KTOP + lane] = sid[lane];
    atomicAdd(counts + sid[lane], 1);
  }
}

__global__ void k_scan(const int* __restrict__ counts, int* __restrict__ offsets){
  if (threadIdx.x == 0){
    int a = 0;
    for (int e = 0; e < NEXP; ++e){ offsets[e] = a; a += counts[e]; }
    offsets[NEXP] = a;
  }
}

__global__ void k_scatter(const int* __restrict__ top_i, const float* __restrict__ top_w,
                          const int* __restrict__ offsets, int* __restrict__ cursor,
                          int* __restrict__ pair_tok, float* __restrict__ pair_w){
  const int t = blockIdx.x * 256 + threadIdx.x;
  if (t >= T_TOK) return;
#pragma unroll
  for (int k = 0; k < KTOP; ++k){
    int e = top_i[t*KTOP + k];
    int pos = offsets[e] + atomicAdd(cursor + e, 1);
    pair_tok[pos] = t;
    pair_w[pos]   = top_w[t*KTOP + k];
  }
}

// ---------------- SwiGLU: act[p][F] = silu(y[p][f]) * y[p][F+f] ----------------
template<int F8>
__global__ __launch_bounds__(256)
void k_swiglu(const unsigned short* __restrict__ y, unsigned short* __restrict__ act){
  const int i = blockIdx.x * 256 + threadIdx.x;
  const int p = i / F8, c = i % F8;
  const unsigned short* row = y + (size_t)p * (2*F8*8);
  short8 g8 = *(const short8*)(row + c*8);
  short8 u8 = *(const short8*)(row + F8*8 + c*8);
  short8 o;
#pragma unroll
  for (int j = 0; j < 8; ++j){
    float g = bf2f((unsigned short)g8[j]);
    float u = bf2f((unsigned short)u8[j]);
    float s = (g / (1.f + expf(-g))) * u;
    o[j] = (short)f2bf(s);
  }
  *(short8*)(act + (size_t)p*F8*8 + c*8) = o;
}

// ---------------- grouped GEMM, 128x128 tile, 4 waves, 3-slot K-32 ring ----------------
// 48 KB LDS -> 3 blocks/CU: cross-block overlap fills barrier stalls (m97/m103 regime).
// A: bf16 [rows][K]; BT: bf16 [e][N][K]; OUT: 0=bf16 store; 1=fp32 atomic*pair_w; 2=fp32 store
template<bool GROUPED, bool GATHER, int OUT>
__global__ __launch_bounds__(256, 3)
void k_gemm(const unsigned short* __restrict__ A,
            const unsigned short* __restrict__ BT,
            void* __restrict__ outp,
            const int* __restrict__ pair_tok, const float* __restrict__ pair_w,
            const int* __restrict__ counts, const int* __restrict__ offsets,
            const int N, const int K, const int ntiles)
{
  const int NH = K >> 5;                 // K-halves of 32
  const int total = gridDim.x;
  const int phys  = blockIdx.x;
  const int logical = (phys & 7) * (total >> 3) + (phys >> 3);
  const int mt   = logical & 31;         // 32 m-tiles of 128
  const int rest = logical >> 5;
  const int n0 = (rest % ntiles) << 7;
  const int e  = rest / ntiles;

  int M, base;
  if (GROUPED){ M = counts[e]; base = offsets[e]; }
  else        { M = T_TOK;     base = 0; }
  if (mt * 128 >= M) return;
  const unsigned short* Bb = BT + (size_t)e * (size_t)N * K;

  __shared__ unsigned short AS[3*4096];  // 3 slots x 128 rows x 32k (24 KB)
  __shared__ unsigned short BS[3*4096];  // 24 KB

  const int tid  = threadIdx.x;
  const int lane = tid & 63;
  const int w    = tid >> 6;             // 0..3
  const int wr = w >> 1, wc = w & 1;     // 2x2 wave grid, wave out = 64x64

  // staging: wave w covers rows w*32..w*32+31 of A and B tiles; 2 insts each
  const int lrow = lane >> 2, lchunk = lane & 3;
  const int swz = (lchunk ^ ((lrow >> 1) & 3)) * 8;   // inverse-swizzled source k-offset
  const unsigned short *ap0, *ap1, *bp0, *bp1;
  {
    const int r0 = w*32 + lrow, r1 = w*32 + 16 + lrow;
    int i0 = min(mt*128 + r0, M - 1);
    int i1 = min(mt*128 + r1, M - 1);
    int rowA0 = GATHER ? pair_tok[base + i0] : (GROUPED ? base + i0 : i0);
    int rowA1 = GATHER ? pair_tok[base + i1] : (GROUPED ? base + i1 : i1);
    ap0 = A + (size_t)rowA0 * K + swz;
    ap1 = A + (size_t)rowA1 * K + swz;
    bp0 = Bb + (size_t)(n0 + r0) * K + swz;
    bp1 = Bb + (size_t)(n0 + r1) * K + swz;
  }

  const f32x4 zero = {0.f,0.f,0.f,0.f};
  f32x4 acc[4][4];
#pragma unroll
  for (int m = 0; m < 4; ++m)
#pragma unroll
    for (int n = 0; n < 4; ++n) acc[m][n] = zero;

  const int fr = lane & 15;
  const int fg = ((lane >> 4) ^ ((lane >> 1) & 3)) * 16;  // swizzled chunk byte offset

#define STAGE(h)                                                            \
  { const int _s = (h) % 3; const size_t _k = (size_t)(h) * 32;             \
    gload_lds16(ap0 + _k, (char*)AS + _s*8192 + (w*32)*64);                 \
    gload_lds16(ap1 + _k, (char*)AS + _s*8192 + (w*32+16)*64);              \
    gload_lds16(bp0 + _k, (char*)BS + _s*8192 + (w*32)*64);                 \
    gload_lds16(bp1 + _k, (char*)BS + _s*8192 + (w*32+16)*64); }

  STAGE(0) STAGE(1)
  asm volatile("s_waitcnt vmcnt(4)" ::: "memory");
  __builtin_amdgcn_s_barrier();

#pragma unroll 6
  for (int h = 0; h < NH; ++h){
    const int s = h % 3;
    const char* _as = (const char*)AS + s*8192;
    const char* _bs = (const char*)BS + s*8192;
    short8 bq[4], af[4];
#pragma unroll
    for (int n = 0; n < 4; ++n)
      bq[n] = *(const short8*)(_bs + (wc*64 + n*16 + fr)*64 + fg);
#pragma unroll
    for (int m = 0; m < 4; ++m)
      af[m] = *(const short8*)(_as + (wr*64 + m*16 + fr)*64 + fg);
    if (h + 2 < NH) STAGE(h + 2)
    __builtin_amdgcn_s_setprio(1);
#pragma unroll
    for (int m = 0; m < 4; ++m)
#pragma unroll
      for (int n = 0; n < 4; ++n)
        acc[m][n] = __builtin_amdgcn_mfma_f32_16x16x32_bf16(af[m], bq[n], acc[m][n], 0, 0, 0);
    __builtin_amdgcn_s_setprio(0);
    if (h + 2 < NH) asm volatile("s_waitcnt vmcnt(4)" ::: "memory");
    else            asm volatile("s_waitcnt vmcnt(0)" ::: "memory");
    __builtin_amdgcn_s_barrier();
  }
#undef STAGE

#pragma unroll
  for (int m = 0; m < 4; ++m)
#pragma unroll
    for (int j = 0; j < 4; ++j){
      const int rr = mt*128 + wr*64 + m*16 + (lane >> 4)*4 + j;
      if (rr < M){
        const int col = n0 + wc*64 + fr;
        if (OUT == 0){
          unsigned short* orow = (unsigned short*)outp + (size_t)(base + rr) * N + col;
#pragma unroll
          for (int n = 0; n < 4; ++n) orow[n*16] = f2bf(acc[m][n][j]);
        } else if (OUT == 1){
          const int p = base + rr;
          const int tok = pair_tok[p];
          const float pw = pair_w[p];
          float* orow = (float*)outp + (size_t)tok * HID + col;
#pragma unroll
          for (int n = 0; n < 4; ++n) atomicAdd(orow + n*16, acc[m][n][j] * pw);
        } else {
          float* orow = (float*)outp + (size_t)rr * N + col;
#pragma unroll
          for (int n = 0; n < 4; ++n) orow[n*16] = acc[m][n][j];
        }
      }
    }
}

extern "C" void kernel_launch(void* const* d_in, const int* in_sizes, int n_in,
                              void* d_out, int out_size, void* d_ws, size_t ws_size,
                              hipStream_t stream)
{
  (void)in_sizes; (void)n_in; (void)out_size; (void)ws_size;
  const float* hid = (const float*)d_in[0];
  const float* rw  = (const float*)d_in[1];
  const float* rb  = (const float*)d_in[2];
  const float* gw  = (const float*)d_in[3];
  const float* uw  = (const float*)d_in[4];
  const float* dw  = (const float*)d_in[5];
  const float* sgw = (const float*)d_in[6];
  const float* suw = (const float*)d_in[7];
  const float* sdw = (const float*)d_in[8];
  float* out = (float*)d_out;

  char* ws = (char*)d_ws;
  size_t o = 0;
  unsigned short* xb   = (unsigned short*)(ws + o); o += (size_t)T_TOK*HID*2;       // 21 MB
  unsigned short* act  = (unsigned short*)(ws + o); o += (size_t)MAXP*FF*2;         // 75.5 MB
  unsigned short* sact = (unsigned short*)(ws + o); o += (size_t)T_TOK*SFF*2;       // 25 MB
  unsigned short* y    = (unsigned short*)(ws + o); o += (size_t)MAXP*2*FF*2;       // 151 MB
  unsigned short* sy   = (unsigned short*)(ws + o); o += (size_t)T_TOK*2*SFF*2;     // 50 MB
  unsigned short* Wbuf = (unsigned short*)(ws + o);
  unsigned short* guT  = Wbuf;                                     // [32][2F][H]
  unsigned short* sguT = Wbuf + (size_t)NEXP*2*FF*HID;             // [2SF][H]
  unsigned short* dT   = Wbuf;                                     // [32][H][F] (reuse)
  unsigned short* sdT  = Wbuf + (size_t)NEXP*HID*FF;               // [H][SF]   (reuse)
  o += (size_t)NEXP*2*FF*HID*2 + (size_t)2*SFF*HID*2;              // 535 MB
  float* top_w    = (float*)(ws + o); o += (size_t)T_TOK*KTOP*4;
  int*   top_i    = (int*)(ws + o);   o += (size_t)T_TOK*KTOP*4;
  float* pair_w   = (float*)(ws + o); o += (size_t)MAXP*4;
  int*   pair_tok = (int*)(ws + o);   o += (size_t)MAXP*4;
  int*   counts   = (int*)(ws + o);   o += NEXP*4;
  int*   offsets  = (int*)(ws + o);   o += (NEXP+1)*4;
  int*   cursor   = (int*)(ws + o);   o += NEXP*4;

  hipMemsetAsync(counts, 0, (NEXP + (NEXP+1) + NEXP) * sizeof(int), stream);

  k_cast_x<<<(T_TOK*HID)/1024, 256, 0, stream>>>(hid, xb);
  k_router<<<T_TOK/4, 256, 0, stream>>>(hid, rw, rb, top_w, top_i, counts);
  k_scan<<<1, 64, 0, stream>>>(counts, offsets);
  k_scatter<<<T_TOK/256, 256, 0, stream>>>(top_i, top_w, offsets, cursor, pair_tok, pair_w);

  // phase A transposes: gate/up concatenated [gate;up] along N
  k_transpose<<<dim3(FF/64,  HID/64, NEXP), 256, 0, stream>>>(gw,  guT,                    HID, FF,  (long long)2*FF*HID);
  k_transpose<<<dim3(FF/64,  HID/64, NEXP), 256, 0, stream>>>(uw,  guT + (size_t)FF*HID,   HID, FF,  (long long)2*FF*HID);
  k_transpose<<<dim3(SFF/64, HID/64, 1),    256, 0, stream>>>(sgw, sguT,                   HID, SFF, 0);
  k_transpose<<<dim3(SFF/64, HID/64, 1),    256, 0, stream>>>(suw, sguT + (size_t)SFF*HID, HID, SFF, 0);

  // gate+up GEMMs (N' = 2F), then SwiGLU
  k_gemm<true,  true,  0><<<32*(2*FF/128)*NEXP, 256, 0, stream>>>(
      xb, guT, y, pair_tok, nullptr, counts, offsets, 2*FF, HID, 2*FF/128);
  k_gemm<false, false, 0><<<32*(2*SFF/128), 256, 0, stream>>>(
      xb, sguT, sy, nullptr, nullptr, nullptr, nullptr, 2*SFF, HID, 2*SFF/128);
  k_swiglu<FF/8><<<(MAXP*(FF/8))/256, 256, 0, stream>>>(y, act);
  k_swiglu<SFF/8><<<(T_TOK*(SFF/8))/256, 256, 0, stream>>>(sy, sact);

  // phase B transposes: down (reuse gate/up region)
  k_transpose<<<dim3(HID/64, FF/64,  NEXP), 256, 0, stream>>>(dw,  dT,  FF,  HID, (long long)HID*FF);
  k_transpose<<<dim3(HID/64, SFF/64, 1),    256, 0, stream>>>(sdw, sdT, SFF, HID, 0);

  // down GEMMs: shared writes out (init), expert atomically accumulates
  k_gemm<false, false, 2><<<32*(HID/128), 256, 0, stream>>>(
      sact, sdT, out, nullptr, nullptr, nullptr, nullptr, HID, SFF, HID/128);
  k_gemm<true,  false, 1><<<32*(HID/128)*NEXP, 256, 0, stream>>>(
      act, dT, out, pair_tok, pair_w, counts, offsets, HID, FF, HID/128);
}